// Round 3
// baseline (161.643 us; speedup 1.0000x reference)
//
#include <hip/hip_runtime.h>
#include <hip/hip_bf16.h>
#include <math.h>

#define C0 8
#define C1 4
#define NCH 20          // C0 + 3*C1
#define NQ 16
#define K3 125
#define G 8
#define NZ 512          // 8^3
#define RMAX 5.5f
#define EPSL 1e-6f

#define TPAD 128        // taps padded 125 -> 128
#define KD1 2048        // gemm1 K = TPAD*16
#define PADV 1728       // 12^3
#define XTP_C 27648     // PADV*16 elements per channel
#define PHI_N 1048576   // 512 * 2048
#define XTP_N 552960    // 20*1728*16
#define W2_N 20480      // 32*20*32
#define KD2 640         // gemm2 K = 20*32

using f32x4 = __attribute__((ext_vector_type(4))) float;
using s16x8 = __attribute__((ext_vector_type(8))) short;
typedef struct { __hip_bfloat16 x, y, z, w; } bf16x4;  // 8 B

__device__ __forceinline__ float epsf(int i, int m, int j) {
    if (i == m || m == j || i == j) return 0.f;
    return (m == (i + 1) % 3) ? 1.f : -1.f;
}

// ---------------- prep: phi (bf16), xtp (bf16), w2 (bf16) ----------------
// phi[(p*32+b)][t*16+q]  b = g*4+mi, mi: 0=R, 1..3 = R*u_{z,y,x}
// xtp[c][az][ay][ax][q]  zero-padded 12^3
// w2 [o=32pad][c=20][b=32]
__global__ __launch_bounds__(256) void prep_kernel(
    const float* __restrict__ x,
    const float* __restrict__ q_in, const float* __restrict__ q_out,
    const float* __restrict__ w_ss, const float* __restrict__ w_vs,
    const float* __restrict__ w_sv, const float* __restrict__ w_vv0,
    const float* __restrict__ w_vv1,
    __hip_bfloat16* __restrict__ phi, __hip_bfloat16* __restrict__ xtp,
    __hip_bfloat16* __restrict__ w2)
{
    int gid = blockIdx.x * 256 + threadIdx.x;   // exact grid: PHI_N+XTP_N+W2_N
    if (gid < PHI_N) {
        int col = gid & (KD1 - 1); int m = gid >> 11;
        int t = col >> 4, q = col & 15;
        int p = m >> 5,  b = m & 31;
        int g = b >> 2,  mi = b & 3;
        float val = 0.f;
        if (t < K3) {
            int tz = t / 25, ty = (t / 5) % 5, tx = t % 5;
            float vz = (float)(tz - 2) - (q_out[p*3+0] - q_in[q*3+0]);
            float vy = (float)(ty - 2) - (q_out[p*3+1] - q_in[q*3+1]);
            float vx = (float)(tx - 2) - (q_out[p*3+2] - q_in[q*3+2]);
            float r  = sqrtf(vz*vz + vy*vy + vx*vx);
            float inv = (r > EPSL) ? (1.0f / r) : 0.0f;
            const float sigma = RMAX / (float)(G - 1);
            float d = (r - (RMAX * (float)g / (float)(G - 1))) / sigma;
            float Rg = expf(-0.5f * d * d);
            float u = (mi == 1) ? vz*inv : ((mi == 2) ? vy*inv : vx*inv);
            val = (mi == 0) ? Rg : Rg * u;
        }
        phi[gid] = __float2bfloat16(val);
    } else if (gid < PHI_N + XTP_N) {
        int g2 = gid - PHI_N;
        int q = g2 & 15; int r = g2 >> 4;
        int ax = r % 12; r /= 12;
        int ay = r % 12; r /= 12;
        int az = r % 12; int c = r / 12;
        int iz = az - 2, iy = ay - 2, ix = ax - 2;
        bool valid = ((unsigned)iz < 8u) & ((unsigned)iy < 8u) & ((unsigned)ix < 8u);
        float v = valid ? x[((c * NQ + q) << 9) + (iz << 6) + (iy << 3) + ix] : 0.f;
        xtp[g2] = __float2bfloat16(v);
    } else {
        int id = gid - (PHI_N + XTP_N);
        int b = id & 31; int r = id >> 5;
        int c = r % NCH; int o = r / NCH;
        int g = b >> 2,  mi = b & 3;
        float val = 0.f;
        if (o < NCH) {
            if (o < C0) {
                if (c < C0) { if (mi == 0) val = w_ss[(o * C0 + c) * G + g]; }
                else { int cv = (c - C0) / 3, j = (c - C0) % 3;
                       if (mi == 1 + j) val = w_sv[(o * C1 + cv) * G + g]; }
            } else {
                int ov = (o - C0) / 3, i = (o - C0) % 3;
                if (c < C0) { if (mi == 1 + i) val = w_vs[(ov * C0 + c) * G + g]; }
                else {
                    int cv = (c - C0) / 3, j = (c - C0) % 3;
                    if (mi == 0) { if (i == j) val = w_vv0[(ov * C1 + cv) * G + g]; }
                    else val = 0.7071067811865476f * w_vv1[(ov * C1 + cv) * G + g]
                               * epsf(i, mi - 1, j);
                }
            }
        }
        w2[id] = __float2bfloat16(val);
    }
}

// ---------------- gemm1: E2[p][c][z][b] = sum_{t,q} phi * xtp ----------------
__global__ __launch_bounds__(256) void gemm1_kernel(
    const short* __restrict__ phi, const short* __restrict__ xtp,
    __hip_bfloat16* __restrict__ E2)
{
    int wave = threadIdx.x >> 6, lane = threadIdx.x & 63;
    int row = lane & 15, quad = lane >> 4;
    int bi = blockIdx.x;                 // 640
    int mb = bi / 40;                    // 0..15  (M-block of 32 rows; p = mb)
    int nb = (bi % 40) * 4 + wave;       // 0..159 (N-block of 64 cols)
    int c  = nb >> 3;                    // 64 | 512 so whole wave same c

    int aoff[2];
    #pragma unroll
    for (int mt = 0; mt < 2; ++mt)
        aoff[mt] = (mb * 32 + mt * 16 + row) * KD1 + quad * 8;

    int boff[4];
    #pragma unroll
    for (int nt = 0; nt < 4; ++nt) {
        int z = (nb * 64 + nt * 16 + row) & 511;
        int zz = z >> 6, zy = (z >> 3) & 7, zx = z & 7;
        boff[nt] = c * XTP_C + zz * 2304 + zy * 192 + zx * 16 + (quad & 1) * 8;
    }
    bool hi = (quad >> 1);               // which t of the k-step's pair

    f32x4 acc[2][4];
    #pragma unroll
    for (int i = 0; i < 2; ++i)
        #pragma unroll
        for (int j = 0; j < 4; ++j) acc[i][j] = (f32x4){0.f, 0.f, 0.f, 0.f};

    #pragma unroll 4
    for (int st = 0; st < 64; ++st) {
        int t0 = st * 2, t1 = t0 + 1;
        int tz0 = t0 / 25, r0 = t0 % 25, ty0 = r0 / 5, tx0 = r0 % 5;
        int tz1 = t1 / 25, r1 = t1 % 25, ty1 = r1 / 5, tx1 = r1 % 5;
        int toffA = tz0 * 2304 + ty0 * 192 + tx0 * 16;
        int toffB = tz1 * 2304 + ty1 * 192 + tx1 * 16;
        int toff = hi ? toffB : toffA;

        s16x8 a[2], b4[4];
        #pragma unroll
        for (int mt = 0; mt < 2; ++mt)
            a[mt] = *(const s16x8*)(phi + aoff[mt] + st * 32);
        #pragma unroll
        for (int nt = 0; nt < 4; ++nt)
            b4[nt] = *(const s16x8*)(xtp + boff[nt] + toff);

        #pragma unroll
        for (int mt = 0; mt < 2; ++mt)
            #pragma unroll
            for (int nt = 0; nt < 4; ++nt)
                acc[mt][nt] = __builtin_amdgcn_mfma_f32_16x16x32_bf16(
                    a[mt], b4[nt], acc[mt][nt], 0, 0, 0);
    }

    // E2[p=mb][c][z][b = mt*16 + quad*4 + ri], 8 B per store
    #pragma unroll
    for (int mt = 0; mt < 2; ++mt) {
        #pragma unroll
        for (int nt = 0; nt < 4; ++nt) {
            int z = (nb * 64 + nt * 16 + row) & 511;
            int baddr = ((mb * NCH + c) * 512 + z) * 32 + mt * 16 + quad * 4;
            bf16x4 v;
            v.x = __float2bfloat16(acc[mt][nt][0]);
            v.y = __float2bfloat16(acc[mt][nt][1]);
            v.z = __float2bfloat16(acc[mt][nt][2]);
            v.w = __float2bfloat16(acc[mt][nt][3]);
            *(bf16x4*)(E2 + baddr) = v;
        }
    }
}

// ---------------- gemm2: out[o][p][z] = sum_{c,b} w2 * E2  (+bias) ----------------
__global__ __launch_bounds__(256) void gemm2_kernel(
    const short* __restrict__ w2, const short* __restrict__ E2,
    const float* __restrict__ bias, float* __restrict__ out)
{
    int wave = threadIdx.x >> 6, lane = threadIdx.x & 63;
    int row = lane & 15, quad = lane >> 4;
    int bi = blockIdx.x;                 // 32
    int p  = bi >> 1;
    int nb = (bi & 1) * 4 + wave;        // 0..7 (z-block of 64)

    int aoff[2];
    #pragma unroll
    for (int mt = 0; mt < 2; ++mt)
        aoff[mt] = (mt * 16 + row) * KD2 + quad * 8;

    int boff[4];
    #pragma unroll
    for (int nt = 0; nt < 4; ++nt) {
        int z = nb * 64 + nt * 16 + row;
        boff[nt] = ((p * NCH) * 512 + z) * 32 + quad * 8;
    }

    f32x4 acc[2][4];
    #pragma unroll
    for (int i = 0; i < 2; ++i)
        #pragma unroll
        for (int j = 0; j < 4; ++j) acc[i][j] = (f32x4){0.f, 0.f, 0.f, 0.f};

    #pragma unroll 5
    for (int st = 0; st < 20; ++st) {    // st = c
        s16x8 a[2], b4[4];
        #pragma unroll
        for (int mt = 0; mt < 2; ++mt)
            a[mt] = *(const s16x8*)(w2 + aoff[mt] + st * 32);
        #pragma unroll
        for (int nt = 0; nt < 4; ++nt)
            b4[nt] = *(const s16x8*)(E2 + boff[nt] + st * (512 * 32));
        #pragma unroll
        for (int mt = 0; mt < 2; ++mt)
            #pragma unroll
            for (int nt = 0; nt < 4; ++nt)
                acc[mt][nt] = __builtin_amdgcn_mfma_f32_16x16x32_bf16(
                    a[mt], b4[nt], acc[mt][nt], 0, 0, 0);
    }

    #pragma unroll
    for (int mt = 0; mt < 2; ++mt) {
        #pragma unroll
        for (int nt = 0; nt < 4; ++nt) {
            int z = nb * 64 + nt * 16 + row;
            #pragma unroll
            for (int ri = 0; ri < 4; ++ri) {
                int o = mt * 16 + quad * 4 + ri;
                if (o < NCH) {
                    float v = acc[mt][nt][ri] + ((o < C0) ? bias[o] : 0.f);
                    out[(o * NQ + p) * 512 + z] = v;
                }
            }
        }
    }
}

extern "C" void kernel_launch(void* const* d_in, const int* in_sizes, int n_in,
                              void* d_out, int out_size, void* d_ws, size_t ws_size,
                              hipStream_t stream) {
    const float* x     = (const float*)d_in[0];
    const float* q_in  = (const float*)d_in[1];
    const float* q_out = (const float*)d_in[2];
    const float* w_ss  = (const float*)d_in[3];
    const float* w_vs  = (const float*)d_in[4];
    const float* w_sv  = (const float*)d_in[5];
    const float* w_vv0 = (const float*)d_in[6];
    const float* w_vv1 = (const float*)d_in[7];
    const float* bias  = (const float*)d_in[8];
    float* out = (float*)d_out;

    char* ws = (char*)d_ws;
    __hip_bfloat16* phi = (__hip_bfloat16*)(ws + 0);          // 2,097,152 B
    __hip_bfloat16* xtp = (__hip_bfloat16*)(ws + 2097152);    // 1,105,920 B
    __hip_bfloat16* w2  = (__hip_bfloat16*)(ws + 3203072);    //    40,960 B
    __hip_bfloat16* E2  = (__hip_bfloat16*)(ws + 3244032);    // 10,485,760 B (total 13.7 MB)

    const int PREP_N = PHI_N + XTP_N + W2_N;                  // 1,622,016 = 6336*256
    hipLaunchKernelGGL(prep_kernel, dim3(PREP_N / 256), dim3(256), 0, stream,
                       x, q_in, q_out, w_ss, w_vs, w_sv, w_vv0, w_vv1, phi, xtp, w2);
    hipLaunchKernelGGL(gemm1_kernel, dim3(640), dim3(256), 0, stream,
                       (const short*)phi, (const short*)xtp, E2);
    hipLaunchKernelGGL(gemm2_kernel, dim3(32), dim3(256), 0, stream,
                       (const short*)w2, (const short*)E2, bias, out);
}

// Round 4
// 151.061 us; speedup vs baseline: 1.0701x; 1.0701x over previous
//
#include <hip/hip_runtime.h>
#include <hip/hip_bf16.h>
#include <math.h>

#define C0 8
#define C1 4
#define NCH 20          // C0 + 3*C1
#define NQ 16
#define K3 125
#define G 8
#define NZ 512          // 8^3
#define RMAX 5.5f
#define EPSL 1e-6f

#define TPAD 128        // taps padded 125 -> 128
#define KD1 2048        // gemm1 K = TPAD*16
#define PADV 1728       // 12^3
#define XTP_C 27648     // PADV*16 elements per channel
#define PHI_N 1048576   // 512 * 2048
#define XTP_N 552960    // 20*1728*16
#define W2_N 20480      // 32*20*32
#define OUT_N 163840    // 320*512
#define KD2 640         // gemm2 K per chunk = 20*32
#define E2_CHUNK 5242880 // 16*20*512*32 elements per kc chunk

using f32x4 = __attribute__((ext_vector_type(4))) float;
using s16x8 = __attribute__((ext_vector_type(8))) short;
typedef struct { __hip_bfloat16 x, y, z, w; } bf16x4;  // 8 B

__device__ __forceinline__ float epsf(int i, int m, int j) {
    if (i == m || m == j || i == j) return 0.f;
    return (m == (i + 1) % 3) ? 1.f : -1.f;
}

// ---------------- prep: phi, xtp, w2 (bf16) + out bias-init ----------------
// phi[(p*32+b)][t*16+q]  b = g*4+mi, mi: 0=R, 1..3 = R*u_{z,y,x}
// xtp[c][az][ay][ax][q]  zero-padded 12^3
// w2 [o=32pad][c=20][b=32]
__global__ __launch_bounds__(256) void prep_kernel(
    const float* __restrict__ x,
    const float* __restrict__ q_in, const float* __restrict__ q_out,
    const float* __restrict__ w_ss, const float* __restrict__ w_vs,
    const float* __restrict__ w_sv, const float* __restrict__ w_vv0,
    const float* __restrict__ w_vv1, const float* __restrict__ bias,
    __hip_bfloat16* __restrict__ phi, __hip_bfloat16* __restrict__ xtp,
    __hip_bfloat16* __restrict__ w2, float* __restrict__ out)
{
    int gid = blockIdx.x * 256 + threadIdx.x;   // exact grid
    if (gid < PHI_N) {
        int col = gid & (KD1 - 1); int m = gid >> 11;
        int t = col >> 4, q = col & 15;
        int p = m >> 5,  b = m & 31;
        int g = b >> 2,  mi = b & 3;
        float val = 0.f;
        if (t < K3) {
            int tz = t / 25, ty = (t / 5) % 5, tx = t % 5;
            float vz = (float)(tz - 2) - (q_out[p*3+0] - q_in[q*3+0]);
            float vy = (float)(ty - 2) - (q_out[p*3+1] - q_in[q*3+1]);
            float vx = (float)(tx - 2) - (q_out[p*3+2] - q_in[q*3+2]);
            float r  = sqrtf(vz*vz + vy*vy + vx*vx);
            float inv = (r > EPSL) ? (1.0f / r) : 0.0f;
            const float sigma = RMAX / (float)(G - 1);
            float d = (r - (RMAX * (float)g / (float)(G - 1))) / sigma;
            float Rg = expf(-0.5f * d * d);
            float u = (mi == 1) ? vz*inv : ((mi == 2) ? vy*inv : vx*inv);
            val = (mi == 0) ? Rg : Rg * u;
        }
        phi[gid] = __float2bfloat16(val);
    } else if (gid < PHI_N + XTP_N) {
        int g2 = gid - PHI_N;
        int q = g2 & 15; int r = g2 >> 4;
        int ax = r % 12; r /= 12;
        int ay = r % 12; r /= 12;
        int az = r % 12; int c = r / 12;
        int iz = az - 2, iy = ay - 2, ix = ax - 2;
        bool valid = ((unsigned)iz < 8u) & ((unsigned)iy < 8u) & ((unsigned)ix < 8u);
        float v = valid ? x[((c * NQ + q) << 9) + (iz << 6) + (iy << 3) + ix] : 0.f;
        xtp[g2] = __float2bfloat16(v);
    } else if (gid < PHI_N + XTP_N + W2_N) {
        int id = gid - (PHI_N + XTP_N);
        int b = id & 31; int r = id >> 5;
        int c = r % NCH; int o = r / NCH;
        int g = b >> 2,  mi = b & 3;
        float val = 0.f;
        if (o < NCH) {
            if (o < C0) {
                if (c < C0) { if (mi == 0) val = w_ss[(o * C0 + c) * G + g]; }
                else { int cv = (c - C0) / 3, j = (c - C0) % 3;
                       if (mi == 1 + j) val = w_sv[(o * C1 + cv) * G + g]; }
            } else {
                int ov = (o - C0) / 3, i = (o - C0) % 3;
                if (c < C0) { if (mi == 1 + i) val = w_vs[(ov * C0 + c) * G + g]; }
                else {
                    int cv = (c - C0) / 3, j = (c - C0) % 3;
                    if (mi == 0) { if (i == j) val = w_vv0[(ov * C1 + cv) * G + g]; }
                    else val = 0.7071067811865476f * w_vv1[(ov * C1 + cv) * G + g]
                               * epsf(i, mi - 1, j);
                }
            }
        }
        w2[id] = __float2bfloat16(val);
    } else {
        int id = gid - (PHI_N + XTP_N + W2_N);   // (o*16+p)*512+z
        int o = id >> 13;
        out[id] = (o < C0) ? bias[o] : 0.f;
    }
}

// ---------------- gemm1: E2[kc][p][c][z][b] = sum_{t in chunk, q} phi * xtp ----------------
// block tile 128x128 (2x2 waves of 64x64), split-K x4 over tap chunks of 32
__global__ __launch_bounds__(256, 3) void gemm1_kernel(
    const short* __restrict__ phi, const short* __restrict__ xtp,
    __hip_bfloat16* __restrict__ E2)
{
    int wave = threadIdx.x >> 6, lane = threadIdx.x & 63;
    int row = lane & 15, quad = lane >> 4;
    int wi = wave >> 1, wj = wave & 1;

    int bi = blockIdx.x;                 // 1280
    int kc = bi / 320;
    int r  = bi - kc * 320;
    int mb = r / 80;                     // 0..3  (M block of 128)
    int nb = r - mb * 80;                // 0..79 (N block of 128)
    int c  = nb >> 2;                    // channel (128 | 512)
    int zbase = (nb & 3) * 128 + wj * 64;
    int mrow  = mb * 128 + wi * 64;

    int aoff[4];
    #pragma unroll
    for (int mt = 0; mt < 4; ++mt)
        aoff[mt] = (mrow + mt * 16 + row) * KD1 + kc * 512 + quad * 8;

    int boff[4];
    #pragma unroll
    for (int nt = 0; nt < 4; ++nt) {
        int z = zbase + nt * 16 + row;
        int zz = z >> 6, zy = (z >> 3) & 7, zx = z & 7;
        boff[nt] = c * XTP_C + zz * 2304 + zy * 192 + zx * 16 + (quad & 1) * 8;
    }
    int hi = quad >> 1;                  // which t of the k-step's pair

    f32x4 acc[4][4];
    #pragma unroll
    for (int i = 0; i < 4; ++i)
        #pragma unroll
        for (int j = 0; j < 4; ++j) acc[i][j] = (f32x4){0.f, 0.f, 0.f, 0.f};

    #pragma unroll 4
    for (int st = 0; st < 16; ++st) {
        int t = kc * 32 + st * 2 + hi;
        int tz = (int)((unsigned)t / 25u);
        int trm = t - tz * 25;
        int ty = (int)((unsigned)trm / 5u);
        int tx = trm - ty * 5;
        int toff = tz * 2304 + ty * 192 + tx * 16;

        s16x8 a[4], b4[4];
        #pragma unroll
        for (int mt = 0; mt < 4; ++mt)
            a[mt] = *(const s16x8*)(phi + aoff[mt] + st * 32);
        #pragma unroll
        for (int nt = 0; nt < 4; ++nt)
            b4[nt] = *(const s16x8*)(xtp + boff[nt] + toff);

        #pragma unroll
        for (int mt = 0; mt < 4; ++mt)
            #pragma unroll
            for (int nt = 0; nt < 4; ++nt)
                acc[mt][nt] = __builtin_amdgcn_mfma_f32_16x16x32_bf16(
                    a[mt], b4[nt], acc[mt][nt], 0, 0, 0);
    }

    // store: E2[kc][p][c][z][b], p = m>>5, b = m&31
    __hip_bfloat16* Ek = E2 + (size_t)kc * E2_CHUNK;
    #pragma unroll
    for (int mt = 0; mt < 4; ++mt) {
        int m0 = mrow + mt * 16 + quad * 4;
        int p = m0 >> 5, b0 = m0 & 31;
        #pragma unroll
        for (int nt = 0; nt < 4; ++nt) {
            int z = zbase + nt * 16 + row;
            int addr = (((p * NCH + c) << 9) + z) * 32 + b0;
            bf16x4 v;
            v.x = __float2bfloat16(acc[mt][nt][0]);
            v.y = __float2bfloat16(acc[mt][nt][1]);
            v.z = __float2bfloat16(acc[mt][nt][2]);
            v.w = __float2bfloat16(acc[mt][nt][3]);
            *(bf16x4*)(Ek + addr) = v;
        }
    }
}

// ---------------- gemm2: out[o][p][z] += sum_{c,b} w2 * E2[kc]  (atomic) ----------------
__global__ __launch_bounds__(256) void gemm2_kernel(
    const short* __restrict__ w2, const short* __restrict__ E2,
    float* __restrict__ out)
{
    int wave = threadIdx.x >> 6, lane = threadIdx.x & 63;
    int row = lane & 15, quad = lane >> 4;
    int bi = blockIdx.x;                 // 128
    int p  = bi >> 3;
    int zh = (bi >> 2) & 1;
    int kc = bi & 3;
    int zbase = zh * 256 + wave * 64;

    const short* Ek = E2 + (size_t)kc * E2_CHUNK;

    int aoff[2];
    #pragma unroll
    for (int mt = 0; mt < 2; ++mt)
        aoff[mt] = (mt * 16 + row) * KD2 + quad * 8;

    int boff[4];
    #pragma unroll
    for (int nt = 0; nt < 4; ++nt) {
        int z = zbase + nt * 16 + row;
        boff[nt] = ((p * NCH) << 9) * 32 + z * 32 + quad * 8;
    }

    f32x4 acc[2][4];
    #pragma unroll
    for (int i = 0; i < 2; ++i)
        #pragma unroll
        for (int j = 0; j < 4; ++j) acc[i][j] = (f32x4){0.f, 0.f, 0.f, 0.f};

    #pragma unroll 4
    for (int st = 0; st < NCH; ++st) {   // st = c
        s16x8 a[2], b4[4];
        #pragma unroll
        for (int mt = 0; mt < 2; ++mt)
            a[mt] = *(const s16x8*)(w2 + aoff[mt] + st * 32);
        #pragma unroll
        for (int nt = 0; nt < 4; ++nt)
            b4[nt] = *(const s16x8*)(Ek + boff[nt] + st * (512 * 32));
        #pragma unroll
        for (int mt = 0; mt < 2; ++mt)
            #pragma unroll
            for (int nt = 0; nt < 4; ++nt)
                acc[mt][nt] = __builtin_amdgcn_mfma_f32_16x16x32_bf16(
                    a[mt], b4[nt], acc[mt][nt], 0, 0, 0);
    }

    #pragma unroll
    for (int mt = 0; mt < 2; ++mt) {
        #pragma unroll
        for (int nt = 0; nt < 4; ++nt) {
            int z = zbase + nt * 16 + row;
            #pragma unroll
            for (int ri = 0; ri < 4; ++ri) {
                int o = mt * 16 + quad * 4 + ri;
                if (o < NCH)
                    atomicAdd(out + ((o * NQ + p) << 9) + z, acc[mt][nt][ri]);
            }
        }
    }
}

extern "C" void kernel_launch(void* const* d_in, const int* in_sizes, int n_in,
                              void* d_out, int out_size, void* d_ws, size_t ws_size,
                              hipStream_t stream) {
    const float* x     = (const float*)d_in[0];
    const float* q_in  = (const float*)d_in[1];
    const float* q_out = (const float*)d_in[2];
    const float* w_ss  = (const float*)d_in[3];
    const float* w_vs  = (const float*)d_in[4];
    const float* w_sv  = (const float*)d_in[5];
    const float* w_vv0 = (const float*)d_in[6];
    const float* w_vv1 = (const float*)d_in[7];
    const float* bias  = (const float*)d_in[8];
    float* out = (float*)d_out;

    char* ws = (char*)d_ws;
    __hip_bfloat16* phi = (__hip_bfloat16*)(ws + 0);          //  2,097,152 B
    __hip_bfloat16* xtp = (__hip_bfloat16*)(ws + 2097152);    //  1,105,920 B
    __hip_bfloat16* w2  = (__hip_bfloat16*)(ws + 3203072);    //     40,960 B
    __hip_bfloat16* E2  = (__hip_bfloat16*)(ws + 3244032);    // 41,943,040 B (total 45.2 MB)

    const int PREP_N = PHI_N + XTP_N + W2_N + OUT_N;          // 1,785,856 = 6976*256
    hipLaunchKernelGGL(prep_kernel, dim3(PREP_N / 256), dim3(256), 0, stream,
                       x, q_in, q_out, w_ss, w_vs, w_sv, w_vv0, w_vv1, bias,
                       phi, xtp, w2, out);
    hipLaunchKernelGGL(gemm1_kernel, dim3(1280), dim3(256), 0, stream,
                       (const short*)phi, (const short*)xtp, E2);
    hipLaunchKernelGGL(gemm2_kernel, dim3(128), dim3(256), 0, stream,
                       (const short*)w2, (const short*)E2, out);
}

// Round 5
// 144.441 us; speedup vs baseline: 1.1191x; 1.0458x over previous
//
#include <hip/hip_runtime.h>
#include <hip/hip_bf16.h>
#include <math.h>

#define C0 8
#define C1 4
#define NCH 20          // C0 + 3*C1
#define NQ 16
#define K3 125
#define G 8
#define RMAX 5.5f
#define EPSL 1e-6f

#define KD1 2048        // gemm1 K = 128 taps * 16 q
#define PHI_N 1048576   // 512 * 2048
#define XTP_N 552960    // 20*1728*16
#define W2_N 20480      // 32*20*32
#define E2_CHUNK 5242880 // elements per kc chunk: 16*20*512*32

using f32x4 = __attribute__((ext_vector_type(4))) float;
using s16x8 = __attribute__((ext_vector_type(8))) short;

__device__ __forceinline__ float epsf(int i, int m, int j) {
    if (i == m || m == j || i == j) return 0.f;
    return (m == (i + 1) % 3) ? 1.f : -1.f;
}

// ---------------- prep: phi, xtp, w2 (bf16) ----------------
// phi[m=p*32+b][t*16+q]  b = g*4+mi, mi: 0=R, 1..3 = R*u_{z,y,x}; t>=125 zero
// xtp[c][az][ay][ax][q]  zero-padded 12^3
// w2 [o=32pad][c=20][b=32]
__global__ __launch_bounds__(256) void prep_kernel(
    const float* __restrict__ x,
    const float* __restrict__ q_in, const float* __restrict__ q_out,
    const float* __restrict__ w_ss, const float* __restrict__ w_vs,
    const float* __restrict__ w_sv, const float* __restrict__ w_vv0,
    const float* __restrict__ w_vv1,
    __hip_bfloat16* __restrict__ phi, __hip_bfloat16* __restrict__ xtp,
    __hip_bfloat16* __restrict__ w2)
{
    int gid = blockIdx.x * 256 + threadIdx.x;   // exact grid
    if (gid < PHI_N) {
        int col = gid & (KD1 - 1); int m = gid >> 11;
        int t = col >> 4, q = col & 15;
        int p = m >> 5,  b = m & 31;
        int g = b >> 2,  mi = b & 3;
        float val = 0.f;
        if (t < K3) {
            int tz = t / 25, ty = (t / 5) % 5, tx = t % 5;
            float vz = (float)(tz - 2) - (q_out[p*3+0] - q_in[q*3+0]);
            float vy = (float)(ty - 2) - (q_out[p*3+1] - q_in[q*3+1]);
            float vx = (float)(tx - 2) - (q_out[p*3+2] - q_in[q*3+2]);
            float r  = sqrtf(vz*vz + vy*vy + vx*vx);
            float inv = (r > EPSL) ? (1.0f / r) : 0.0f;
            const float sigma = RMAX / (float)(G - 1);
            float d = (r - (RMAX * (float)g / (float)(G - 1))) / sigma;
            float Rg = expf(-0.5f * d * d);
            float u = (mi == 1) ? vz*inv : ((mi == 2) ? vy*inv : vx*inv);
            val = (mi == 0) ? Rg : Rg * u;
        }
        phi[gid] = __float2bfloat16(val);
    } else if (gid < PHI_N + XTP_N) {
        int g2 = gid - PHI_N;
        int q = g2 & 15; int r = g2 >> 4;
        int ax = r % 12; r /= 12;
        int ay = r % 12; r /= 12;
        int az = r % 12; int c = r / 12;
        int iz = az - 2, iy = ay - 2, ix = ax - 2;
        bool valid = ((unsigned)iz < 8u) & ((unsigned)iy < 8u) & ((unsigned)ix < 8u);
        float v = valid ? x[((c * NQ + q) << 9) + (iz << 6) + (iy << 3) + ix] : 0.f;
        xtp[g2] = __float2bfloat16(v);
    } else {
        int id = gid - (PHI_N + XTP_N);
        int b = id & 31; int r = id >> 5;
        int c = r % NCH; int o = r / NCH;
        int g = b >> 2,  mi = b & 3;
        float val = 0.f;
        if (o < NCH) {
            if (o < C0) {
                if (c < C0) { if (mi == 0) val = w_ss[(o * C0 + c) * G + g]; }
                else { int cv = (c - C0) / 3, j = (c - C0) % 3;
                       if (mi == 1 + j) val = w_sv[(o * C1 + cv) * G + g]; }
            } else {
                int ov = (o - C0) / 3, i = (o - C0) % 3;
                if (c < C0) { if (mi == 1 + i) val = w_vs[(ov * C0 + c) * G + g]; }
                else {
                    int cv = (c - C0) / 3, j = (c - C0) % 3;
                    if (mi == 0) { if (i == j) val = w_vv0[(ov * C1 + cv) * G + g]; }
                    else val = 0.7071067811865476f * w_vv1[(ov * C1 + cv) * G + g]
                               * epsf(i, mi - 1, j);
                }
            }
        }
        w2[id] = __float2bfloat16(val);
    }
}

// ---------------- gemm1: LDS-staged, E2[kc][p][c][z][b] ----------------
// block: 256 thr (4 waves, 2x2 of 64x64), tile 128m x 128z, c fixed, split-K x4
__global__ __launch_bounds__(256, 3) void gemm1_kernel(
    const char* __restrict__ phi_b, const char* __restrict__ xtp_b,
    __hip_bfloat16* __restrict__ E2)
{
    __shared__ __align__(16) char lds[16384 + 27648];  // A piece-major | B halo slab

    int tid = threadIdx.x;
    int wave = tid >> 6, lane = tid & 63;
    int row = lane & 15, quad = lane >> 4;
    int wi = wave >> 1, wj = wave & 1;

    int bi = blockIdx.x;                 // 1280
    int kc = bi / 320;
    int r  = bi - kc * 320;
    int mb = r / 80;                     // m-tile of 128
    int nb = r - mb * 80;
    int c  = nb >> 2;                    // channel
    int zq = nb & 3;                     // z-tile of 128

    // ---- B slab: xtp[c][az = zq*2 .. zq*2+5][ay][ax][q], 27648 B contiguous ----
    {
        const char* src = xtp_b + c * 55296 + zq * 9216;
        for (int i = tid; i < 1728; i += 256) {
            s16x8 v = *(const s16x8*)(src + i * 16);
            *(s16x8*)(lds + 16384 + i * 16) = v;
        }
    }

    // ---- A staging: slot s -> piece = s>>7, m = s&127 ; lds byte = s*16 ----
    const char* abase = phi_b + (size_t)(mb * 128) * 4096 + kc * 1024;
    int sm[4], sp[4];
    #pragma unroll
    for (int i = 0; i < 4; ++i) { int s = tid + i * 256; sm[i] = s & 127; sp[i] = s >> 7; }
    s16x8 areg[4];
    #pragma unroll
    for (int i = 0; i < 4; ++i)
        areg[i] = *(const s16x8*)(abase + sm[i] * 4096 + sp[i] * 16);

    // per-lane B bases (bytes into lds)
    int bpre[4];
    #pragma unroll
    for (int nt = 0; nt < 4; ++nt) {
        int zl = wj * 64 + nt * 16 + row;
        int zz = zl >> 6, zy = (zl >> 3) & 7, zx = zl & 7;
        bpre[nt] = 16384 + (zz * 144 + zy * 12 + zx) * 32 + (quad & 1) * 16;
    }
    int hi = quad >> 1;

    f32x4 acc[4][4];
    #pragma unroll
    for (int i = 0; i < 4; ++i)
        #pragma unroll
        for (int j = 0; j < 4; ++j) acc[i][j] = (f32x4){0.f, 0.f, 0.f, 0.f};

    for (int j = 0; j < 8; ++j) {
        // tap byte-offsets for this chunk's 4 taps (wave-uniform)
        int tb = kc * 32 + j * 4;
        int toff[4];
        #pragma unroll
        for (int tt = 0; tt < 4; ++tt) {
            int t = tb + tt; if (t > 124) t = 124;   // pad taps: phi=0, keep addr in-bounds
            int tz = t / 25, trm = t - tz * 25;
            int ty = trm / 5, tx = trm - ty * 5;
            toff[tt] = (tz * 144 + ty * 12 + tx) * 32;
        }
        // commit A chunk j to LDS
        #pragma unroll
        for (int i = 0; i < 4; ++i)
            *(s16x8*)(lds + (tid + i * 256) * 16) = areg[i];
        __syncthreads();
        // prefetch A chunk j+1 into registers (flies during compute)
        if (j < 7) {
            #pragma unroll
            for (int i = 0; i < 4; ++i)
                areg[i] = *(const s16x8*)(abase + sm[i] * 4096 + (j + 1) * 128 + sp[i] * 16);
        }
        // compute: 2 k-steps of 32
        #pragma unroll
        for (int st = 0; st < 2; ++st) {
            s16x8 af[4], bf[4];
            #pragma unroll
            for (int mt = 0; mt < 4; ++mt)
                af[mt] = *(const s16x8*)(lds + (st * 4 + quad) * 2048
                                             + (wi * 64 + mt * 16 + row) * 16);
            int tsel = toff[st * 2 + hi];
            #pragma unroll
            for (int nt = 0; nt < 4; ++nt)
                bf[nt] = *(const s16x8*)(lds + bpre[nt] + tsel);
            #pragma unroll
            for (int mt = 0; mt < 4; ++mt)
                #pragma unroll
                for (int nt = 0; nt < 4; ++nt)
                    acc[mt][nt] = __builtin_amdgcn_mfma_f32_16x16x32_bf16(
                        af[mt], bf[nt], acc[mt][nt], 0, 0, 0);
        }
        __syncthreads();
    }

    // epilogue: nontemporal 8B stores, E2[kc][p][c][z][b]
    __hip_bfloat16* Ek = E2 + (size_t)kc * E2_CHUNK;
    #pragma unroll
    for (int mt = 0; mt < 4; ++mt) {
        int m0 = mb * 128 + wi * 64 + mt * 16 + quad * 4;
        int p = m0 >> 5, b0 = m0 & 31;
        #pragma unroll
        for (int nt = 0; nt < 4; ++nt) {
            int z = zq * 128 + wj * 64 + nt * 16 + row;
            union { unsigned long long u; __hip_bfloat16 h[4]; } pk;
            pk.h[0] = __float2bfloat16(acc[mt][nt][0]);
            pk.h[1] = __float2bfloat16(acc[mt][nt][1]);
            pk.h[2] = __float2bfloat16(acc[mt][nt][2]);
            pk.h[3] = __float2bfloat16(acc[mt][nt][3]);
            __builtin_nontemporal_store(pk.u,
                (unsigned long long*)(Ek + (((p * NCH + c) << 9) + z) * 32 + b0));
        }
    }
}

// ---------------- gemm2: out[o][p][z] = bias + sum_{kc,c,b} w2 * E2 ----------------
// 256 blocks x 128 thr; block = (p, z32 tile); wave = one z16 column group
__global__ __launch_bounds__(128) void gemm2_kernel(
    const char* __restrict__ w2_b, const char* __restrict__ E2_b,
    const float* __restrict__ bias, float* __restrict__ out)
{
    int tid = threadIdx.x;
    int wave = tid >> 6, lane = tid & 63;
    int row = lane & 15, quad = lane >> 4;
    int bi = blockIdx.x;                 // 256
    int p  = bi >> 4;
    int zb = bi & 15;
    int z  = zb * 32 + wave * 16 + row;

    const char* bbase = E2_b + ((size_t)((p * NCH) << 9) * 32 + (size_t)z * 32 + quad * 8) * 2;

    f32x4 acc[2];
    acc[0] = (f32x4){0.f, 0.f, 0.f, 0.f};
    acc[1] = (f32x4){0.f, 0.f, 0.f, 0.f};

    for (int kc = 0; kc < 4; ++kc) {
        const char* bk = bbase + (size_t)kc * (E2_CHUNK * 2);
        #pragma unroll 5
        for (int cc = 0; cc < NCH; ++cc) {
            s16x8 a0 = *(const s16x8*)(w2_b + (row)      * 1280 + cc * 64 + quad * 16);
            s16x8 a1 = *(const s16x8*)(w2_b + (16 + row) * 1280 + cc * 64 + quad * 16);
            s16x8 b  = *(const s16x8*)(bk + (size_t)cc * 32768);
            acc[0] = __builtin_amdgcn_mfma_f32_16x16x32_bf16(a0, b, acc[0], 0, 0, 0);
            acc[1] = __builtin_amdgcn_mfma_f32_16x16x32_bf16(a1, b, acc[1], 0, 0, 0);
        }
    }

    #pragma unroll
    for (int mt = 0; mt < 2; ++mt)
        #pragma unroll
        for (int ri = 0; ri < 4; ++ri) {
            int o = mt * 16 + quad * 4 + ri;
            if (o < NCH)
                out[((o * NQ + p) << 9) + z] = acc[mt][ri] + ((o < C0) ? bias[o] : 0.f);
        }
}

extern "C" void kernel_launch(void* const* d_in, const int* in_sizes, int n_in,
                              void* d_out, int out_size, void* d_ws, size_t ws_size,
                              hipStream_t stream) {
    const float* x     = (const float*)d_in[0];
    const float* q_in  = (const float*)d_in[1];
    const float* q_out = (const float*)d_in[2];
    const float* w_ss  = (const float*)d_in[3];
    const float* w_vs  = (const float*)d_in[4];
    const float* w_sv  = (const float*)d_in[5];
    const float* w_vv0 = (const float*)d_in[6];
    const float* w_vv1 = (const float*)d_in[7];
    const float* bias  = (const float*)d_in[8];
    float* out = (float*)d_out;

    char* ws = (char*)d_ws;
    __hip_bfloat16* phi = (__hip_bfloat16*)(ws + 0);          //  2,097,152 B
    __hip_bfloat16* xtp = (__hip_bfloat16*)(ws + 2097152);    //  1,105,920 B
    __hip_bfloat16* w2  = (__hip_bfloat16*)(ws + 3203072);    //     40,960 B
    __hip_bfloat16* E2  = (__hip_bfloat16*)(ws + 3244032);    // 41,943,040 B (total 45.2 MB)

    const int PREP_N = PHI_N + XTP_N + W2_N;                  // 1,622,016 = 6336*256
    hipLaunchKernelGGL(prep_kernel, dim3(PREP_N / 256), dim3(256), 0, stream,
                       x, q_in, q_out, w_ss, w_vs, w_sv, w_vv0, w_vv1, phi, xtp, w2);
    hipLaunchKernelGGL(gemm1_kernel, dim3(1280), dim3(256), 0, stream,
                       (const char*)phi, (const char*)xtp, E2);
    hipLaunchKernelGGL(gemm2_kernel, dim3(256), dim3(128), 0, stream,
                       (const char*)w2, (const char*)E2, bias, out);
}

// Round 6
// 117.288 us; speedup vs baseline: 1.3782x; 1.2315x over previous
//
#include <hip/hip_runtime.h>
#include <hip/hip_bf16.h>
#include <math.h>

#define C0 8
#define C1 4
#define NCH 20          // C0 + 3*C1
#define NQ 16
#define K3 125
#define G 8
#define RMAX 5.5f
#define EPSL 1e-6f

#define KD1 2048        // gemm1 K = 128 taps * 16 q
#define PHI_N 1048576   // 512 * 2048
#define XTP_N 552960    // 20*1728*16
#define W2_N 20480      // 32*20*32
#define KD2 640         // gemm2 K per kc chunk = 20*32
#define E2C_B 10485760  // bytes per kc chunk of E2: 16*20*512*32*2

#define LDS_A 18432     // 128 rows * 144 B (128 B data + 16 pad)
#define LDS_B 27648     // 6*12*12*16 bf16 slab

using f32x4 = __attribute__((ext_vector_type(4))) float;
using s16x8 = __attribute__((ext_vector_type(8))) short;

__device__ __forceinline__ float epsf(int i, int m, int j) {
    if (i == m || m == j || i == j) return 0.f;
    return (m == (i + 1) % 3) ? 1.f : -1.f;
}

// ---------------- prep: phi, xtp, w2 (bf16) ----------------
// phi[m=p*32+b][t*16+q]  b = g*4+mi, mi: 0=R, 1..3 = R*u_{z,y,x}; t>=125 zero
// xtp[c][az][ay][ax][q]  zero-padded 12^3
// w2 [o=32pad][c=20][b=32]
__global__ __launch_bounds__(256) void prep_kernel(
    const float* __restrict__ x,
    const float* __restrict__ q_in, const float* __restrict__ q_out,
    const float* __restrict__ w_ss, const float* __restrict__ w_vs,
    const float* __restrict__ w_sv, const float* __restrict__ w_vv0,
    const float* __restrict__ w_vv1,
    __hip_bfloat16* __restrict__ phi, __hip_bfloat16* __restrict__ xtp,
    __hip_bfloat16* __restrict__ w2)
{
    int gid = blockIdx.x * 256 + threadIdx.x;   // exact grid
    if (gid < PHI_N) {
        int col = gid & (KD1 - 1); int m = gid >> 11;
        int t = col >> 4, q = col & 15;
        int p = m >> 5,  b = m & 31;
        int g = b >> 2,  mi = b & 3;
        float val = 0.f;
        if (t < K3) {
            int tz = t / 25, ty = (t / 5) % 5, tx = t % 5;
            float vz = (float)(tz - 2) - (q_out[p*3+0] - q_in[q*3+0]);
            float vy = (float)(ty - 2) - (q_out[p*3+1] - q_in[q*3+1]);
            float vx = (float)(tx - 2) - (q_out[p*3+2] - q_in[q*3+2]);
            float r  = sqrtf(vz*vz + vy*vy + vx*vx);
            float inv = (r > EPSL) ? (1.0f / r) : 0.0f;
            const float sigma = RMAX / (float)(G - 1);
            float d = (r - (RMAX * (float)g / (float)(G - 1))) / sigma;
            float Rg = expf(-0.5f * d * d);
            float u = (mi == 1) ? vz*inv : ((mi == 2) ? vy*inv : vx*inv);
            val = (mi == 0) ? Rg : Rg * u;
        }
        phi[gid] = __float2bfloat16(val);
    } else if (gid < PHI_N + XTP_N) {
        int g2 = gid - PHI_N;
        int q = g2 & 15; int r = g2 >> 4;
        int ax = r % 12; r /= 12;
        int ay = r % 12; r /= 12;
        int az = r % 12; int c = r / 12;
        int iz = az - 2, iy = ay - 2, ix = ax - 2;
        bool valid = ((unsigned)iz < 8u) & ((unsigned)iy < 8u) & ((unsigned)ix < 8u);
        float v = valid ? x[((c * NQ + q) << 9) + (iz << 6) + (iy << 3) + ix] : 0.f;
        xtp[g2] = __float2bfloat16(v);
    } else {
        int id = gid - (PHI_N + XTP_N);
        int b = id & 31; int r = id >> 5;
        int c = r % NCH; int o = r / NCH;
        int g = b >> 2,  mi = b & 3;
        float val = 0.f;
        if (o < NCH) {
            if (o < C0) {
                if (c < C0) { if (mi == 0) val = w_ss[(o * C0 + c) * G + g]; }
                else { int cv = (c - C0) / 3, j = (c - C0) % 3;
                       if (mi == 1 + j) val = w_sv[(o * C1 + cv) * G + g]; }
            } else {
                int ov = (o - C0) / 3, i = (o - C0) % 3;
                if (c < C0) { if (mi == 1 + i) val = w_vs[(ov * C0 + c) * G + g]; }
                else {
                    int cv = (c - C0) / 3, j = (c - C0) % 3;
                    if (mi == 0) { if (i == j) val = w_vv0[(ov * C1 + cv) * G + g]; }
                    else val = 0.7071067811865476f * w_vv1[(ov * C1 + cv) * G + g]
                               * epsf(i, mi - 1, j);
                }
            }
        }
        w2[id] = __float2bfloat16(val);
    }
}

// ---------------- gemm1: LDS-staged, sector-efficient, E2[kc][p][c][z][b] ----------------
// grid 640 = kc(2) x pg(4: 128 m-rows = 4 p's) x c(20) x zq(4: 128 z)
// block 256 thr = 2x2 waves of 64x64; 16 chunks of 64 k-elems (4 taps)
__global__ __launch_bounds__(256, 3) void gemm1_kernel(
    const char* __restrict__ phi_b, const char* __restrict__ xtp_b,
    char* __restrict__ E2_b)
{
    __shared__ __align__(16) char lds[LDS_A + LDS_B];

    int tid = threadIdx.x;
    int wave = tid >> 6, lane = tid & 63;
    int row = lane & 15, quad = lane >> 4;
    int wi = wave >> 1, wj = wave & 1;

    int bi = blockIdx.x;                 // 640
    int kc = bi / 320;
    int r  = bi - kc * 320;
    int pg = r / 80;
    int r2 = r - pg * 80;
    int c  = r2 >> 2;
    int zq = r2 & 3;

    // ---- B slab: xtp[c][az = 2zq .. 2zq+5][ay][ax][q], contiguous 27648 B ----
    {
        const char* src = xtp_b + c * 55296 + zq * 9216;
        for (int i = tid; i < 1728; i += 256)
            *(s16x8*)(lds + LDS_A + i * 16) = *(const s16x8*)(src + i * 16);
    }

    // ---- A staging: slot s -> (row = s>>3, kp = s&7); 8 lanes = 128 B contiguous ----
    const char* abase = phi_b + (size_t)(pg * 128) * 4096 + kc * 2048;
    int srow[4], skp[4];
    #pragma unroll
    for (int i = 0; i < 4; ++i) { int s = tid + i * 256; srow[i] = s >> 3; skp[i] = s & 7; }
    s16x8 areg[4];
    #pragma unroll
    for (int i = 0; i < 4; ++i)
        areg[i] = *(const s16x8*)(abase + srow[i] * 4096 + skp[i] * 16);

    // per-lane B LDS pre-offsets
    int bpre[4];
    #pragma unroll
    for (int nt = 0; nt < 4; ++nt) {
        int zl = wj * 64 + nt * 16 + row;
        int zz = zl >> 6, zy = (zl >> 3) & 7, zx = zl & 7;
        bpre[nt] = LDS_A + (zz * 144 + zy * 12 + zx) * 32 + (quad & 1) * 16;
    }
    int hi = quad >> 1;

    f32x4 acc[4][4];
    #pragma unroll
    for (int i = 0; i < 4; ++i)
        #pragma unroll
        for (int j = 0; j < 4; ++j) acc[i][j] = (f32x4){0.f, 0.f, 0.f, 0.f};

    for (int j = 0; j < 16; ++j) {
        int toff[4];
        #pragma unroll
        for (int tt = 0; tt < 4; ++tt) {
            int t = kc * 64 + j * 4 + tt; if (t > 124) t = 124;  // pad taps: phi=0
            int tz = t / 25, trm = t - tz * 25;
            int ty = trm / 5, tx = trm - ty * 5;
            toff[tt] = (tz * 144 + ty * 12 + tx) * 32;
        }
        // commit A chunk j (row-major, padded rows)
        #pragma unroll
        for (int i = 0; i < 4; ++i)
            *(s16x8*)(lds + srow[i] * 144 + skp[i] * 16) = areg[i];
        __syncthreads();
        if (j < 15) {
            #pragma unroll
            for (int i = 0; i < 4; ++i)
                areg[i] = *(const s16x8*)(abase + srow[i] * 4096 + (j + 1) * 128 + skp[i] * 16);
        }
        #pragma unroll
        for (int st = 0; st < 2; ++st) {
            s16x8 af[4], bf[4];
            #pragma unroll
            for (int mt = 0; mt < 4; ++mt)
                af[mt] = *(const s16x8*)(lds + (wi * 64 + mt * 16 + row) * 144
                                             + (st * 4 + quad) * 16);
            int tsel = toff[st * 2 + hi];
            #pragma unroll
            for (int nt = 0; nt < 4; ++nt)
                bf[nt] = *(const s16x8*)(lds + bpre[nt] + tsel);
            #pragma unroll
            for (int mt = 0; mt < 4; ++mt)
                #pragma unroll
                for (int nt = 0; nt < 4; ++nt)
                    acc[mt][nt] = __builtin_amdgcn_mfma_f32_16x16x32_bf16(
                        af[mt], bf[nt], acc[mt][nt], 0, 0, 0);
        }
        __syncthreads();
    }
    // final __syncthreads above: all compute done; LDS reusable

    // ---- epilogue: wave-private LDS transpose -> 1KB-contiguous stores ----
    int wbase = wave * 8704;                     // 64 zl x 136 B
    #pragma unroll
    for (int mt = 0; mt < 4; ++mt) {
        #pragma unroll
        for (int nt = 0; nt < 4; ++nt) {
            int zl = nt * 16 + row;
            union { unsigned long long u; __hip_bfloat16 h[4]; } pk;
            pk.h[0] = __float2bfloat16(acc[mt][nt][0]);
            pk.h[1] = __float2bfloat16(acc[mt][nt][1]);
            pk.h[2] = __float2bfloat16(acc[mt][nt][2]);
            pk.h[3] = __float2bfloat16(acc[mt][nt][3]);
            *(unsigned long long*)(lds + wbase + zl * 136 + (mt * 16 + quad * 4) * 2) = pk.u;
        }
    }
    // wave-local exchange: no barrier needed
    char* Ek = E2_b + (size_t)kc * E2C_B;
    int pbase = pg * 4 + wi * 2;
    #pragma unroll
    for (int it = 0; it < 8; ++it) {
        int item = lane + it * 64;
        int piece = item & 3;
        int zl = (item >> 2) & 63;
        int h  = item >> 8;
        s16x8 v = *(const s16x8*)(lds + wbase + zl * 136 + h * 64 + piece * 16);
        int p = pbase + h;
        int z = zq * 128 + wj * 64 + zl;
        *(s16x8*)(Ek + ((size_t)((p * NCH + c) << 9) + z) * 64 + piece * 16) = v;
    }
}

// ---------------- gemm2: out[o][p][z] = bias + sum_{kc,c,b} w2 * E2 ----------------
// 256 blocks x 128 thr; block = (p, z32 tile); wave = one z16 column group
__global__ __launch_bounds__(128) void gemm2_kernel(
    const char* __restrict__ w2_b, const char* __restrict__ E2_b,
    const float* __restrict__ bias, float* __restrict__ out)
{
    int tid = threadIdx.x;
    int wave = tid >> 6, lane = tid & 63;
    int row = lane & 15, quad = lane >> 4;
    int bi = blockIdx.x;                 // 256
    int p  = bi >> 4;
    int zb = bi & 15;
    int z  = zb * 32 + wave * 16 + row;

    const char* bbase = E2_b + (size_t)p * 655360 + (size_t)z * 64 + quad * 16;

    f32x4 acc[2];
    acc[0] = (f32x4){0.f, 0.f, 0.f, 0.f};
    acc[1] = (f32x4){0.f, 0.f, 0.f, 0.f};

    for (int kc = 0; kc < 2; ++kc) {
        const char* bk = bbase + (size_t)kc * E2C_B;
        #pragma unroll 5
        for (int cc = 0; cc < NCH; ++cc) {
            s16x8 a0 = *(const s16x8*)(w2_b + (row)      * 1280 + cc * 64 + quad * 16);
            s16x8 a1 = *(const s16x8*)(w2_b + (16 + row) * 1280 + cc * 64 + quad * 16);
            s16x8 b  = *(const s16x8*)(bk + (size_t)cc * 32768);
            acc[0] = __builtin_amdgcn_mfma_f32_16x16x32_bf16(a0, b, acc[0], 0, 0, 0);
            acc[1] = __builtin_amdgcn_mfma_f32_16x16x32_bf16(a1, b, acc[1], 0, 0, 0);
        }
    }

    #pragma unroll
    for (int mt = 0; mt < 2; ++mt)
        #pragma unroll
        for (int ri = 0; ri < 4; ++ri) {
            int o = mt * 16 + quad * 4 + ri;
            if (o < NCH)
                out[((o * NQ + p) << 9) + z] = acc[mt][ri] + ((o < C0) ? bias[o] : 0.f);
        }
}

extern "C" void kernel_launch(void* const* d_in, const int* in_sizes, int n_in,
                              void* d_out, int out_size, void* d_ws, size_t ws_size,
                              hipStream_t stream) {
    const float* x     = (const float*)d_in[0];
    const float* q_in  = (const float*)d_in[1];
    const float* q_out = (const float*)d_in[2];
    const float* w_ss  = (const float*)d_in[3];
    const float* w_vs  = (const float*)d_in[4];
    const float* w_sv  = (const float*)d_in[5];
    const float* w_vv0 = (const float*)d_in[6];
    const float* w_vv1 = (const float*)d_in[7];
    const float* bias  = (const float*)d_in[8];
    float* out = (float*)d_out;

    char* ws = (char*)d_ws;
    __hip_bfloat16* phi = (__hip_bfloat16*)(ws + 0);          //  2,097,152 B
    __hip_bfloat16* xtp = (__hip_bfloat16*)(ws + 2097152);    //  1,105,920 B
    __hip_bfloat16* w2  = (__hip_bfloat16*)(ws + 3203072);    //     40,960 B
    char*           E2  = (char*)(ws + 3244032);              // 20,971,520 B (total 24.2 MB)

    const int PREP_N = PHI_N + XTP_N + W2_N;                  // 1,622,016 = 6336*256
    hipLaunchKernelGGL(prep_kernel, dim3(PREP_N / 256), dim3(256), 0, stream,
                       x, q_in, q_out, w_ss, w_vs, w_sv, w_vv0, w_vv1, phi, xtp, w2);
    hipLaunchKernelGGL(gemm1_kernel, dim3(640), dim3(256), 0, stream,
                       (const char*)phi, (const char*)xtp, E2);
    hipLaunchKernelGGL(gemm2_kernel, dim3(256), dim3(128), 0, stream,
                       (const char*)w2, (const char*)E2, bias, out);
}

// Round 7
// 114.272 us; speedup vs baseline: 1.4145x; 1.0264x over previous
//
#include <hip/hip_runtime.h>
#include <hip/hip_bf16.h>
#include <math.h>

#define C0 8
#define C1 4
#define NCH 20          // C0 + 3*C1
#define NQ 16
#define K3 125
#define G 8
#define RMAX 5.5f
#define EPSL 1e-6f

#define KD1 2048        // gemm1 K = 128 taps * 16 q
#define PHI_N 1048576   // 512 * 2048
#define XTP_N 552960    // 20*1728*16
#define W2_N 20480      // 32*20*32
#define OUT_N 163840    // 320*512
#define E2C_B 10485760  // bytes per kc chunk of E2: 16*20*512*32*2

#define LDS_A 18432     // 128 rows * 144 B (128 B data + 16 pad)
#define LDS_B 27648     // 6*12*12*16 bf16 slab

using f32x4 = __attribute__((ext_vector_type(4))) float;
using s16x8 = __attribute__((ext_vector_type(8))) short;

__device__ __forceinline__ float epsf(int i, int m, int j) {
    if (i == m || m == j || i == j) return 0.f;
    return (m == (i + 1) % 3) ? 1.f : -1.f;
}

// ---------------- prep: phi, xtp, w2 (bf16) + out bias-init ----------------
// phi[m=p*32+b][t*16+q]  b = g*4+mi, mi: 0=R, 1..3 = R*u_{z,y,x}; t>=125 zero
// xtp[c][az][ay][ax][q]  zero-padded 12^3
// w2 [o=32pad][c=20][b=32]
__global__ __launch_bounds__(256) void prep_kernel(
    const float* __restrict__ x,
    const float* __restrict__ q_in, const float* __restrict__ q_out,
    const float* __restrict__ w_ss, const float* __restrict__ w_vs,
    const float* __restrict__ w_sv, const float* __restrict__ w_vv0,
    const float* __restrict__ w_vv1, const float* __restrict__ bias,
    __hip_bfloat16* __restrict__ phi, __hip_bfloat16* __restrict__ xtp,
    __hip_bfloat16* __restrict__ w2, float* __restrict__ out)
{
    int gid = blockIdx.x * 256 + threadIdx.x;   // exact grid
    if (gid < PHI_N) {
        int col = gid & (KD1 - 1); int m = gid >> 11;
        int t = col >> 4, q = col & 15;
        int p = m >> 5,  b = m & 31;
        int g = b >> 2,  mi = b & 3;
        float val = 0.f;
        if (t < K3) {
            int tz = t / 25, ty = (t / 5) % 5, tx = t % 5;
            float vz = (float)(tz - 2) - (q_out[p*3+0] - q_in[q*3+0]);
            float vy = (float)(ty - 2) - (q_out[p*3+1] - q_in[q*3+1]);
            float vx = (float)(tx - 2) - (q_out[p*3+2] - q_in[q*3+2]);
            float r  = sqrtf(vz*vz + vy*vy + vx*vx);
            float inv = (r > EPSL) ? (1.0f / r) : 0.0f;
            const float sigma = RMAX / (float)(G - 1);
            float d = (r - (RMAX * (float)g / (float)(G - 1))) / sigma;
            float Rg = expf(-0.5f * d * d);
            float u = (mi == 1) ? vz*inv : ((mi == 2) ? vy*inv : vx*inv);
            val = (mi == 0) ? Rg : Rg * u;
        }
        phi[gid] = __float2bfloat16(val);
    } else if (gid < PHI_N + XTP_N) {
        int g2 = gid - PHI_N;
        int q = g2 & 15; int r = g2 >> 4;
        int ax = r % 12; r /= 12;
        int ay = r % 12; r /= 12;
        int az = r % 12; int c = r / 12;
        int iz = az - 2, iy = ay - 2, ix = ax - 2;
        bool valid = ((unsigned)iz < 8u) & ((unsigned)iy < 8u) & ((unsigned)ix < 8u);
        float v = valid ? x[((c * NQ + q) << 9) + (iz << 6) + (iy << 3) + ix] : 0.f;
        xtp[g2] = __float2bfloat16(v);
    } else if (gid < PHI_N + XTP_N + W2_N) {
        int id = gid - (PHI_N + XTP_N);
        int b = id & 31; int r = id >> 5;
        int c = r % NCH; int o = r / NCH;
        int g = b >> 2,  mi = b & 3;
        float val = 0.f;
        if (o < NCH) {
            if (o < C0) {
                if (c < C0) { if (mi == 0) val = w_ss[(o * C0 + c) * G + g]; }
                else { int cv = (c - C0) / 3, j = (c - C0) % 3;
                       if (mi == 1 + j) val = w_sv[(o * C1 + cv) * G + g]; }
            } else {
                int ov = (o - C0) / 3, i = (o - C0) % 3;
                if (c < C0) { if (mi == 1 + i) val = w_vs[(ov * C0 + c) * G + g]; }
                else {
                    int cv = (c - C0) / 3, j = (c - C0) % 3;
                    if (mi == 0) { if (i == j) val = w_vv0[(ov * C1 + cv) * G + g]; }
                    else val = 0.7071067811865476f * w_vv1[(ov * C1 + cv) * G + g]
                               * epsf(i, mi - 1, j);
                }
            }
        }
        w2[id] = __float2bfloat16(val);
    } else {
        int id = gid - (PHI_N + XTP_N + W2_N);   // (o*16+p)*512+z
        int o = id >> 13;
        out[id] = (o < C0) ? bias[o] : 0.f;
    }
}

// ---------------- gemm1: LDS-staged, sector-efficient, E2[kc][p][c][z][b] ----------------
// grid 640 = kc(2) x pg(4: 128 m-rows = 4 p's) x c(20) x zq(4: 128 z)
// block 256 thr = 2x2 waves of 64x64; 16 chunks of 64 k-elems (4 taps)
__global__ __launch_bounds__(256, 3) void gemm1_kernel(
    const char* __restrict__ phi_b, const char* __restrict__ xtp_b,
    char* __restrict__ E2_b)
{
    __shared__ __align__(16) char lds[LDS_A + LDS_B];

    int tid = threadIdx.x;
    int wave = tid >> 6, lane = tid & 63;
    int row = lane & 15, quad = lane >> 4;
    int wi = wave >> 1, wj = wave & 1;

    int bi = blockIdx.x;                 // 640
    int kc = bi / 320;
    int r  = bi - kc * 320;
    int pg = r / 80;
    int r2 = r - pg * 80;
    int c  = r2 >> 2;
    int zq = r2 & 3;

    // ---- B slab: xtp[c][az = 2zq .. 2zq+5][ay][ax][q], contiguous 27648 B ----
    {
        const char* src = xtp_b + c * 55296 + zq * 9216;
        for (int i = tid; i < 1728; i += 256)
            *(s16x8*)(lds + LDS_A + i * 16) = *(const s16x8*)(src + i * 16);
    }

    // ---- A staging: slot s -> (row = s>>3, kp = s&7); 8 lanes = 128 B contiguous ----
    const char* abase = phi_b + (size_t)(pg * 128) * 4096 + kc * 2048;
    int srow[4], skp[4];
    #pragma unroll
    for (int i = 0; i < 4; ++i) { int s = tid + i * 256; srow[i] = s >> 3; skp[i] = s & 7; }
    s16x8 areg[4];
    #pragma unroll
    for (int i = 0; i < 4; ++i)
        areg[i] = *(const s16x8*)(abase + srow[i] * 4096 + skp[i] * 16);

    // per-lane B LDS pre-offsets
    int bpre[4];
    #pragma unroll
    for (int nt = 0; nt < 4; ++nt) {
        int zl = wj * 64 + nt * 16 + row;
        int zz = zl >> 6, zy = (zl >> 3) & 7, zx = zl & 7;
        bpre[nt] = LDS_A + (zz * 144 + zy * 12 + zx) * 32 + (quad & 1) * 16;
    }
    int hi = quad >> 1;

    f32x4 acc[4][4];
    #pragma unroll
    for (int i = 0; i < 4; ++i)
        #pragma unroll
        for (int j = 0; j < 4; ++j) acc[i][j] = (f32x4){0.f, 0.f, 0.f, 0.f};

    for (int j = 0; j < 16; ++j) {
        int toff[4];
        #pragma unroll
        for (int tt = 0; tt < 4; ++tt) {
            int t = kc * 64 + j * 4 + tt; if (t > 124) t = 124;  // pad taps: phi=0
            int tz = t / 25, trm = t - tz * 25;
            int ty = trm / 5, tx = trm - ty * 5;
            toff[tt] = (tz * 144 + ty * 12 + tx) * 32;
        }
        // commit A chunk j (row-major, padded rows)
        #pragma unroll
        for (int i = 0; i < 4; ++i)
            *(s16x8*)(lds + srow[i] * 144 + skp[i] * 16) = areg[i];
        __syncthreads();
        if (j < 15) {
            #pragma unroll
            for (int i = 0; i < 4; ++i)
                areg[i] = *(const s16x8*)(abase + srow[i] * 4096 + (j + 1) * 128 + skp[i] * 16);
        }
        #pragma unroll
        for (int st = 0; st < 2; ++st) {
            s16x8 af[4], bf[4];
            #pragma unroll
            for (int mt = 0; mt < 4; ++mt)
                af[mt] = *(const s16x8*)(lds + (wi * 64 + mt * 16 + row) * 144
                                             + (st * 4 + quad) * 16);
            int tsel = toff[st * 2 + hi];
            #pragma unroll
            for (int nt = 0; nt < 4; ++nt)
                bf[nt] = *(const s16x8*)(lds + bpre[nt] + tsel);
            #pragma unroll
            for (int mt = 0; mt < 4; ++mt)
                #pragma unroll
                for (int nt = 0; nt < 4; ++nt)
                    acc[mt][nt] = __builtin_amdgcn_mfma_f32_16x16x32_bf16(
                        af[mt], bf[nt], acc[mt][nt], 0, 0, 0);
        }
        __syncthreads();
    }
    // final __syncthreads above: all compute done; LDS reusable

    // ---- epilogue: wave-private LDS transpose -> 1KB-contiguous stores ----
    int wbase = wave * 8704;                     // 64 zl x 136 B
    #pragma unroll
    for (int mt = 0; mt < 4; ++mt) {
        #pragma unroll
        for (int nt = 0; nt < 4; ++nt) {
            int zl = nt * 16 + row;
            union { unsigned long long u; __hip_bfloat16 h[4]; } pk;
            pk.h[0] = __float2bfloat16(acc[mt][nt][0]);
            pk.h[1] = __float2bfloat16(acc[mt][nt][1]);
            pk.h[2] = __float2bfloat16(acc[mt][nt][2]);
            pk.h[3] = __float2bfloat16(acc[mt][nt][3]);
            *(unsigned long long*)(lds + wbase + zl * 136 + (mt * 16 + quad * 4) * 2) = pk.u;
        }
    }
    // wave-local exchange: no barrier needed
    char* Ek = E2_b + (size_t)kc * E2C_B;
    int pbase = pg * 4 + wi * 2;
    #pragma unroll
    for (int it = 0; it < 8; ++it) {
        int item = lane + it * 64;
        int piece = item & 3;
        int zl = (item >> 2) & 63;
        int h  = item >> 8;
        s16x8 v = *(const s16x8*)(lds + wbase + zl * 136 + h * 64 + piece * 16);
        int p = pbase + h;
        int z = zq * 128 + wj * 64 + zl;
        *(s16x8*)(Ek + ((size_t)((p * NCH + c) << 9) + z) * 64 + piece * 16) = v;
    }
}

// ---------------- gemm2: out[o][p][z] += sum_{c-half, b} w2 * E2[kc]  (atomic) ----------------
// 1024 blocks x 128 thr = p(16) x zb(16) x kc(2) x ch(2); 10-iteration K chain
__global__ __launch_bounds__(128) void gemm2_kernel(
    const char* __restrict__ w2_b, const char* __restrict__ E2_b,
    float* __restrict__ out)
{
    int tid = threadIdx.x;
    int wave = tid >> 6, lane = tid & 63;
    int row = lane & 15, quad = lane >> 4;
    int bi = blockIdx.x;                 // 1024
    int p  = bi >> 6;
    int zb = (bi >> 2) & 15;
    int kc = (bi >> 1) & 1;
    int ch = bi & 1;
    int z  = zb * 32 + wave * 16 + row;

    const char* bbase = E2_b + (size_t)kc * E2C_B + (size_t)p * 655360
                        + (size_t)z * 64 + quad * 16;

    f32x4 acc[2];
    acc[0] = (f32x4){0.f, 0.f, 0.f, 0.f};
    acc[1] = (f32x4){0.f, 0.f, 0.f, 0.f};

    #pragma unroll 5
    for (int ci = 0; ci < 10; ++ci) {
        int cc = ch * 10 + ci;
        s16x8 a0 = *(const s16x8*)(w2_b + (row)      * 1280 + cc * 64 + quad * 16);
        s16x8 a1 = *(const s16x8*)(w2_b + (16 + row) * 1280 + cc * 64 + quad * 16);
        s16x8 b  = *(const s16x8*)(bbase + (size_t)cc * 32768);
        acc[0] = __builtin_amdgcn_mfma_f32_16x16x32_bf16(a0, b, acc[0], 0, 0, 0);
        acc[1] = __builtin_amdgcn_mfma_f32_16x16x32_bf16(a1, b, acc[1], 0, 0, 0);
    }

    #pragma unroll
    for (int mt = 0; mt < 2; ++mt)
        #pragma unroll
        for (int ri = 0; ri < 4; ++ri) {
            int o = mt * 16 + quad * 4 + ri;
            if (o < NCH)
                atomicAdd(out + ((o * NQ + p) << 9) + z, acc[mt][ri]);
        }
}

extern "C" void kernel_launch(void* const* d_in, const int* in_sizes, int n_in,
                              void* d_out, int out_size, void* d_ws, size_t ws_size,
                              hipStream_t stream) {
    const float* x     = (const float*)d_in[0];
    const float* q_in  = (const float*)d_in[1];
    const float* q_out = (const float*)d_in[2];
    const float* w_ss  = (const float*)d_in[3];
    const float* w_vs  = (const float*)d_in[4];
    const float* w_sv  = (const float*)d_in[5];
    const float* w_vv0 = (const float*)d_in[6];
    const float* w_vv1 = (const float*)d_in[7];
    const float* bias  = (const float*)d_in[8];
    float* out = (float*)d_out;

    char* ws = (char*)d_ws;
    __hip_bfloat16* phi = (__hip_bfloat16*)(ws + 0);          //  2,097,152 B
    __hip_bfloat16* xtp = (__hip_bfloat16*)(ws + 2097152);    //  1,105,920 B
    __hip_bfloat16* w2  = (__hip_bfloat16*)(ws + 3203072);    //     40,960 B
    char*           E2  = (char*)(ws + 3244032);              // 20,971,520 B (total 24.2 MB)

    const int PREP_N = PHI_N + XTP_N + W2_N + OUT_N;          // 1,785,856 = 6976*256
    hipLaunchKernelGGL(prep_kernel, dim3(PREP_N / 256), dim3(256), 0, stream,
                       x, q_in, q_out, w_ss, w_vs, w_sv, w_vv0, w_vv1, bias,
                       phi, xtp, w2, out);
    hipLaunchKernelGGL(gemm1_kernel, dim3(640), dim3(256), 0, stream,
                       (const char*)phi, (const char*)xtp, E2);
    hipLaunchKernelGGL(gemm2_kernel, dim3(1024), dim3(128), 0, stream,
                       (const char*)w2, (const char*)E2, out);
}